// Round 10
// baseline (702.715 us; speedup 1.0000x reference)
//
#include <hip/hip_runtime.h>
#include <hip/hip_bf16.h>

// EPiC network, round 10: LDS-resident weights + 512-thread WGs (2 waves/SIMD).
// - Weights pre-split (hi/lo bf16) and pre-swizzled to frag order (r9): a
//   fragment read is ds_read_b128 at blockbase + lane*16 (conflict-free,
//   byte-compatible with global_load_lds lane-contiguous DMA).
// - epic WG: 512 thr / 8 waves, 64 pts per wave, 256 WGs, 1 WG/CU (LDS ~159 KB).
//   2 waves/SIMD -> MFMA of one wave overlaps VALU/LDS stalls of the other.
// - Truncating hi-split: hi = x & 0xffff0000 (1 op), lo = RNE(x - hi).
// - xl state: fp32 16-pt-group frag layout (r8):
//   value(p,F) at xlf[(p>>4)*2048 + (F>>4)*256 + (((F>>2)&3)*16+(p&15))*4 + (F&3)]
// - Winner-tail global path + agent-scope write-through publication (r7).
// - Split-bf16 3-term emulation: A*B ~= Ah*Bh + Al*Bh + Ah*Bl.

typedef __attribute__((ext_vector_type(8))) short short8;
typedef __attribute__((ext_vector_type(4))) float f32x4;

#define B_ 16
#define N_ 8192
#define DC_ 16
#define H_ 128
#define G_ 10
#define NB_ 6
#define NEG_ 0.01f

__device__ __forceinline__ float lrelu(float x) { return x > 0.f ? x : NEG_ * x; }

__device__ __forceinline__ unsigned short f2bf(float x) {
  union { float f; unsigned u; } v; v.f = x;
  return (unsigned short)((v.u + 0x7fffu + ((v.u >> 16) & 1u)) >> 16);  // RNE
}
__device__ __forceinline__ float bf2f(unsigned short u) {
  union { unsigned u; float f; } v; v.u = ((unsigned)u) << 16; return v.f;
}
// truncating hi (1 op) + RNE lo of residual; pair represents x to ~2^-17
__device__ __forceinline__ void split_bf(float x, unsigned short& h, unsigned short& l) {
  union { float f; unsigned u; } v; v.f = x;
  unsigned hu = v.u & 0xffff0000u;
  h = (unsigned short)(hu >> 16);
  union { unsigned u; float f; } hv; hv.u = hu;
  l = f2bf(x - hv.f);
}

__device__ __forceinline__ f32x4 mfma16(short8 a, short8 b, f32x4 c) {
  return __builtin_amdgcn_mfma_f32_16x16x32_bf16(a, b, c, 0, 0, 0);
}

__device__ __forceinline__ void make_frags(f32x4 v0, f32x4 v1, short8& bh, short8& bl) {
  unsigned short h, l;
#pragma unroll
  for (int j = 0; j < 4; ++j) {
    split_bf(v0[j], h, l);
    bh[j] = (short)h; bl[j] = (short)l;
  }
#pragma unroll
  for (int j = 0; j < 4; ++j) {
    split_bf(v1[j], h, l);
    bh[4 + j] = (short)h; bl[4 + j] = (short)l;
  }
}

// async 16B-per-lane global -> LDS copy (lane-contiguous DMA)
__device__ __forceinline__ void async_cp16(const void* g, void* l) {
  __builtin_amdgcn_global_load_lds(
      (const __attribute__((address_space(1))) void*)g,
      (__attribute__((address_space(3))) void*)l, 16, 0, 0);
}

// agent-scope write-through publication (no L2 flush)
__device__ __forceinline__ void agent_store(float* p, float v) {
  __hip_atomic_store(p, v, __ATOMIC_RELAXED, __HIP_MEMORY_SCOPE_AGENT);
}
__device__ __forceinline__ float agent_load(const float* p) {
  return __hip_atomic_load(p, __ATOMIC_RELAXED, __HIP_MEMORY_SCOPE_AGENT);
}

// ---- common tail: pool(NS slots) -> h_g -> xg residual -> folded gbias ----
// Works for blockDim 256 or 512: compute guarded, barriers unconditional.
template <int NS>
__device__ void epic_global_tail(
    int b, int tid, const float* __restrict__ pP, float cnt,
    const float* __restrict__ xg_cur, float* __restrict__ xg_next,
    const float* __restrict__ context,
    const float* __restrict__ g1w_n, const float* __restrict__ g1b_n,
    const float* __restrict__ g2w_n, const float* __restrict__ g2b_n,
    const float* __restrict__ l1w_n, const float* __restrict__ l1b_n,
    float* __restrict__ gbias_out, float* shx) {
  if (tid < 256) {
    const int f = tid & 127, kh = tid >> 7;
    const float* pr = pP + ((size_t)b * NS + kh * (NS / 2)) * 128 + f;
    float s = 0.f;
#pragma unroll 8
    for (int w = 0; w < NS / 2; ++w) s += agent_load(pr + w * 128);
    shx[tid] = s;
  }
  __syncthreads();
  if (tid < 128) {
    float s = shx[tid] + shx[tid + 128];
    shx[384 + tid] = s;
    shx[256 + tid] = s / cnt;
  }
  if (tid < G_) shx[512 + tid] = xg_cur[tid];
  if (tid >= 32 && tid < 32 + DC_) shx[522 + tid - 32] = context[b * DC_ + tid - 32];
  __syncthreads();
  if (tid < 256) {
    const int f = tid & 127, kh = tid >> 7;
    const float* wr = g1w_n + (size_t)f * 282 + kh * 142;
    const float* vp = shx + 256 + kh * 142;
    const int n2 = kh ? 70 : 71;
    float a = 0.f;
#pragma unroll 8
    for (int j = 0; j < n2; ++j) {
      float2 w2 = *(const float2*)(wr + 2 * j);
      a += w2.x * vp[2 * j] + w2.y * vp[2 * j + 1];
    }
    shx[tid] = a;  // writes 0..255; reads were 256..539 (disjoint)
  }
  __syncthreads();
  if (tid < 128) shx[544 + tid] = lrelu(shx[tid] + shx[tid + 128] + g1b_n[tid]);
  __syncthreads();
  if (tid < G_) {
    const float* wr = g2w_n + tid * 128;
    float a = g2b_n[tid] + shx[512 + tid];
#pragma unroll 8
    for (int j = 0; j < 32; ++j) {
      float4 w4 = *(const float4*)(wr + 4 * j);
      a += w4.x * shx[544 + 4 * j] + w4.y * shx[544 + 4 * j + 1] +
           w4.z * shx[544 + 4 * j + 2] + w4.w * shx[544 + 4 * j + 3];
    }
    float v = lrelu(a);
    shx[672 + tid] = v;
    xg_next[tid] = v;
  }
  __syncthreads();
  if (tid < 128) {
    const float* wr = l1w_n + tid * 154;
    float a = l1b_n[tid];
#pragma unroll
    for (int j = 0; j < G_; ++j) a += wr[128 + j] * shx[672 + j];
#pragma unroll
    for (int j = 0; j < DC_; ++j) a += wr[138 + j] * shx[522 + j];
    gbias_out[tid] = a;
  }
}

// ---------------- weight prep: split + frag-order swizzle ----------------
// dest off for (F,k): mt=F>>4, r=F&15, ks=k>>5, c=k&31:
//   (mt*4+ks)*512 + ((c>>3)*16 + r)*8 + (c&7)
__global__ __launch_bounds__(256) void prep_weights(
    const float* __restrict__ l1w, const float* __restrict__ l2w,
    unsigned short* __restrict__ w1h, unsigned short* __restrict__ w1l,
    unsigned short* __restrict__ w2h, unsigned short* __restrict__ w2l,
    unsigned int* __restrict__ counters) {
  int idx = blockIdx.x * 256 + threadIdx.x;
  const int total = NB_ * H_ * H_;
  if (idx < 112) counters[idx] = 0u;
  if (idx < total) {
    int i = idx / (H_ * H_), rem = idx % (H_ * H_);
    int F = rem / H_, k = rem % H_;
    int mt = F >> 4, r = F & 15, ks = k >> 5, c = k & 31;
    int off = i * 16384 + (mt * 4 + ks) * 512 + ((c >> 3) * 16 + r) * 8 + (c & 7);
    unsigned short h, l;
    split_bf(l1w[(i * H_ + F) * 154 + k], h, l);
    w1h[off] = h; w1l[off] = l;
    split_bf(l2w[(i * H_ + F) * H_ + k], h, l);
    w2h[off] = h; w2l[off] = l;
  }
}

// ---------------- projection local (writes 16-pt-group xl) + proj/blk0 tail ----
__global__ __launch_bounds__(256, 2) void proj_local_kernel(
    const float* __restrict__ xloc, const float* __restrict__ maskp,
    const float* __restrict__ plw, const float* __restrict__ plb,
    float* __restrict__ xlf, float* __restrict__ pP,
    float* __restrict__ cntp, float* __restrict__ cnt_g,
    unsigned int* __restrict__ counters,
    const float* __restrict__ context,
    const float* __restrict__ g0w, const float* __restrict__ g0b,
    const float* __restrict__ g1pw, const float* __restrict__ g1pb,
    const float* __restrict__ g2pw, const float* __restrict__ g2pb,
    float* __restrict__ xg_g,
    const float* __restrict__ g1w0, const float* __restrict__ g1b0,
    const float* __restrict__ g2w0, const float* __restrict__ g2b0,
    const float* __restrict__ l1w0, const float* __restrict__ l1b0,
    float* __restrict__ gbias_g) {
  __shared__ float wq[H_][4];
  __shared__ float wsum[512];
  __shared__ float cw[4];
  __shared__ float shx[768];
  __shared__ int winflag;
  const int tid = threadIdx.x, bid = blockIdx.x;
  const int wv = tid >> 6, lane = tid & 63;
  const int q = lane >> 4, n16 = lane & 15;
  const int b = bid >> 6;
  if (tid < H_) {
    wq[tid][0] = plw[tid * 3 + 0];
    wq[tid][1] = plw[tid * 3 + 1];
    wq[tid][2] = plw[tid * 3 + 2];
    wq[tid][3] = plb[tid];
  }
  __syncthreads();
  const int t = bid * 4 + wv;            // 32-pt tile index
  const int p0 = t * 32;
  const int pa = p0 + n16, pb = p0 + 16 + n16;
  const float xa0 = xloc[pa * 3], xa1 = xloc[pa * 3 + 1], xa2 = xloc[pa * 3 + 2];
  const float xb0 = xloc[pb * 3], xb1 = xloc[pb * 3 + 1], xb2 = xloc[pb * 3 + 2];
  const float m0 = maskp[pa], m1 = maskp[pb];
  float* ga = xlf + (size_t)(2 * t) * 2048;
  float* gb = ga + 2048;
#pragma unroll
  for (int ms = 0; ms < 8; ++ms) {
    f32x4 v0, v1;
#pragma unroll
    for (int r = 0; r < 4; ++r) {
      const int F = ms * 16 + q * 4 + r;
      float4 w4 = *(const float4*)wq[F];
      v0[r] = lrelu(w4.x * xa0 + w4.y * xa1 + w4.z * xa2 + w4.w) * m0;
      v1[r] = lrelu(w4.x * xb0 + w4.y * xb1 + w4.z * xb2 + w4.w) * m1;
    }
    *(f32x4*)(ga + ms * 256 + (q * 16 + n16) * 4) = v0;
    *(f32x4*)(gb + ms * 256 + (q * 16 + n16) * 4) = v1;
    f32x4 s = v0 + v1;
#pragma unroll
    for (int r = 0; r < 4; ++r) {
      float sv = s[r];
      sv += __shfl_xor(sv, 1, 64);
      sv += __shfl_xor(sv, 2, 64);
      sv += __shfl_xor(sv, 4, 64);
      sv += __shfl_xor(sv, 8, 64);
      s[r] = sv;
    }
    if (n16 == 0) *(f32x4*)&wsum[wv * 128 + ms * 16 + q * 4] = s;
  }
  {
    float c = (q == 0) ? (m0 + m1) : 0.f;
    c += __shfl_xor(c, 1, 64);
    c += __shfl_xor(c, 2, 64);
    c += __shfl_xor(c, 4, 64);
    c += __shfl_xor(c, 8, 64);
    if (lane == 0) cw[wv] = c;
  }
  __syncthreads();
  // two 64-pt slots per WG -> 128 slots per batch
  if (tid < 128) {
    agent_store(&pP[(size_t)(2 * bid) * 128 + tid], wsum[tid] + wsum[128 + tid]);
    agent_store(&pP[(size_t)(2 * bid + 1) * 128 + tid], wsum[256 + tid] + wsum[384 + tid]);
  }
  if (tid == 0) agent_store(&cntp[bid], cw[0] + cw[1] + cw[2] + cw[3]);

  // ---- winner tail: proj global path + block-0 global path ----
  __syncthreads();
  if (tid == 0) winflag = (atomicAdd(&counters[b], 1u) == 63u) ? 1 : 0;
  __syncthreads();
  if (!winflag) return;
  if (tid < 64) shx[688 + tid] = agent_load(&cntp[b * 64 + tid]);
  __syncthreads();
  if (tid == 0) {
    float c = 0.f;
#pragma unroll
    for (int w = 0; w < 64; ++w) c += shx[688 + w];
    shx[752] = c;
    cnt_g[b] = c;
  }
  __syncthreads();
  const float cnt = shx[752];
  {
    const int f = tid & 127, kh = tid >> 7;
    const float* pr = pP + ((size_t)b * 128 + kh * 64) * 128 + f;
    float s = 0.f;
#pragma unroll 8
    for (int w = 0; w < 64; ++w) s += agent_load(pr + w * 128);
    shx[tid] = s;
  }
  __syncthreads();
  if (tid < 128) {
    float s = shx[tid] + shx[tid + 128];
    shx[384 + tid] = s;
    shx[256 + tid] = s / cnt;
  }
  if (tid < DC_) shx[512 + tid] = context[b * DC_ + tid];
  __syncthreads();
  {
    const int f = tid & 127, kh = tid >> 7;
    const float* wr = g0w + (size_t)f * 272 + kh * 136;
    const float* vp = shx + 256 + kh * 136;
    float a = 0.f;
#pragma unroll 8
    for (int j = 0; j < 34; ++j) {
      float4 w4 = *(const float4*)(wr + 4 * j);
      a += w4.x * vp[4 * j] + w4.y * vp[4 * j + 1] + w4.z * vp[4 * j + 2] + w4.w * vp[4 * j + 3];
    }
    __syncthreads();
    shx[tid] = a;
  }
  __syncthreads();
  if (tid < 128) shx[544 + tid] = lrelu(shx[tid] + shx[tid + 128] + g0b[tid]);
  __syncthreads();
  {
    const int f = tid & 127, kh = tid >> 7;
    const float* wr = g1pw + (size_t)f * 128 + kh * 64;
    const float* vp = shx + 544 + kh * 64;
    float a = 0.f;
#pragma unroll 8
    for (int j = 0; j < 16; ++j) {
      float4 w4 = *(const float4*)(wr + 4 * j);
      a += w4.x * vp[4 * j] + w4.y * vp[4 * j + 1] + w4.z * vp[4 * j + 2] + w4.w * vp[4 * j + 3];
    }
    __syncthreads();
    shx[tid] = a;
  }
  __syncthreads();
  if (tid < 128) shx[544 + tid] = lrelu(shx[tid] + shx[tid + 128] + g1pb[tid]);
  __syncthreads();
  if (tid < G_) {
    const float* wr = g2pw + tid * 128;
    float a = g2pb[tid];
#pragma unroll 8
    for (int j = 0; j < 32; ++j) {
      float4 w4 = *(const float4*)(wr + 4 * j);
      a += w4.x * shx[544 + 4 * j] + w4.y * shx[544 + 4 * j + 1] +
           w4.z * shx[544 + 4 * j + 2] + w4.w * shx[544 + 4 * j + 3];
    }
    xg_g[(0 * 16 + b) * 16 + tid] = lrelu(a);
  }
  __syncthreads();
  epic_global_tail<128>(b, tid, pP, cnt,
                        xg_g + (0 * 16 + b) * 16, xg_g + (1 * 16 + b) * 16, context,
                        g1w0, g1b0, g2w0, g2b0, l1w0, l1b0,
                        gbias_g + (size_t)(0 * 16 + b) * 128, shx);
}

// ---------------- epic local: LDS-weight GEMMs, 8 waves x 64 pts ----------------
template <bool LAST>
__global__ __launch_bounds__(512, 2) void epic_local_kernel(
    float* __restrict__ xlf, float* __restrict__ pP,
    const float* __restrict__ cnt_g, unsigned int* __restrict__ counters_blk,
    const float* __restrict__ gbias_in,
    const float* __restrict__ xg_tail_cur, float* __restrict__ xg_tail_next,
    float* __restrict__ gbias_tail_out,
    const float* __restrict__ context,
    const float* __restrict__ g1w_n, const float* __restrict__ g1b_n,
    const float* __restrict__ g2w_n, const float* __restrict__ g2b_n,
    const float* __restrict__ l1w_n, const float* __restrict__ l1b_n,
    const float* __restrict__ l2b,
    const unsigned short* __restrict__ w1h, const unsigned short* __restrict__ w1l,
    const unsigned short* __restrict__ w2h, const unsigned short* __restrict__ w2l,
    const float* __restrict__ maskp,
    const float* __restrict__ outw, const float* __restrict__ outb,
    float* __restrict__ outp) {
  __shared__ unsigned short wbuf[65536];  // 128 KB: w1h|w1l|w2h|w2l, 16384 shorts each
  __shared__ float tiles[8][576];
  __shared__ float shx[768];
  __shared__ float gbias_s[128];
  __shared__ float l2b_s[128];
  __shared__ float wsum[1024];
  __shared__ float outw_s[392];
  __shared__ int winflag;
  const int tid = threadIdx.x, bid = blockIdx.x;
  const int b = bid >> 4;  // 16 WGs per batch
  const int wv = tid >> 6, lane = tid & 63;
  const int q = lane >> 4, n16 = lane & 15;

  // ---- stage weights: wave wv stages 16 KB (16 x 1KB async) ----
  {
    const unsigned short* src =
        (wv < 2) ? w1h : (wv < 4) ? w1l : (wv < 6) ? w2h : w2l;
    const char* s8 = (const char*)(src + (wv & 1) * 8192) + lane * 16;
    char* d8 = (char*)wbuf + wv * 16384;
#pragma unroll
    for (int j = 0; j < 16; ++j) async_cp16(s8 + j * 1024, d8 + j * 1024);
  }
  if (tid < 128) {
    gbias_s[tid] = gbias_in[b * 128 + tid];
    l2b_s[tid] = l2b[tid];
  }
  if (LAST) {
    if (tid < 384) outw_s[tid] = outw[tid];
    if (tid >= 384 && tid < 387) outw_s[tid] = outb[tid - 384];
  }

  // ---- x B-frags for 4 groups (64 points): 64 VGPR persistent ----
  const int g0i = bid * 32 + wv * 4;  // first 16-pt group of this wave
  short8 xbh[4][4], xbl[4][4];
#pragma unroll
  for (int nt = 0; nt < 4; ++nt) {
    const float* base_nt = xlf + (size_t)(g0i + nt) * 2048;
#pragma unroll
    for (int ks = 0; ks < 4; ++ks) {
      const float* pb = base_nt + (2 * ks + (q >> 1)) * 256 + ((q & 1) * 32 + n16) * 4;
      f32x4 v0 = *(const f32x4*)pb;
      f32x4 v1 = *(const f32x4*)(pb + 64);
      make_frags(v0, v1, xbh[nt][ks], xbl[nt][ks]);
    }
  }
  __syncthreads();  // staging drained (vmcnt 0) + all waves ready

  const unsigned short* w1h_l = wbuf;
  const unsigned short* w1l_l = wbuf + 16384;
  const unsigned short* w2h_l = wbuf + 32768;
  const unsigned short* w2l_l = wbuf + 49152;
  float* T = tiles[wv];
  const int lane16 = lane * 8;  // shorts

  f32x4 acc2[4][8];
#pragma unroll
  for (int nt = 0; nt < 4; ++nt)
#pragma unroll
    for (int ms = 0; ms < 8; ++ms) acc2[nt][ms] = (f32x4){0.f, 0.f, 0.f, 0.f};

#pragma unroll
  for (int ko = 0; ko < 4; ++ko) {
    // ---- GEMM1: w1 frags from LDS ----
    short8 a1h[2][4], a1l[2][4];
#pragma unroll
    for (int msl = 0; msl < 2; ++msl)
#pragma unroll
      for (int ks = 0; ks < 4; ++ks) {
        const int off = ((ko * 2 + msl) * 4 + ks) * 512 + lane16;
        a1h[msl][ks] = *(const short8*)(w1h_l + off);
        a1l[msl][ks] = *(const short8*)(w1l_l + off);
      }
    f32x4 acc[4][2];
#pragma unroll
    for (int nt = 0; nt < 4; ++nt)
#pragma unroll
      for (int msl = 0; msl < 2; ++msl) acc[nt][msl] = (f32x4){0.f, 0.f, 0.f, 0.f};
#pragma unroll
    for (int ks = 0; ks < 4; ++ks)
#pragma unroll
      for (int msl = 0; msl < 2; ++msl)
#pragma unroll
        for (int nt = 0; nt < 4; ++nt) {
          acc[nt][msl] = mfma16(a1h[msl][ks], xbh[nt][ks], acc[nt][msl]);
          acc[nt][msl] = mfma16(a1l[msl][ks], xbh[nt][ks], acc[nt][msl]);
          acc[nt][msl] = mfma16(a1h[msl][ks], xbl[nt][ks], acc[nt][msl]);
        }
    // ---- per nt: lrelu+gbias, tile round-trip -> b2 frags ----
    short8 b2h[4], b2l[4];
#pragma unroll
    for (int nt = 0; nt < 4; ++nt) {
#pragma unroll
      for (int msl = 0; msl < 2; ++msl) {
        f32x4 gb4 = *(const f32x4*)&gbias_s[(ko * 2 + msl) * 16 + q * 4];
        f32x4 hv;
#pragma unroll
        for (int r = 0; r < 4; ++r) hv[r] = lrelu(acc[nt][msl][r] + gb4[r]);
        *(f32x4*)&T[n16 * 36 + msl * 16 + q * 4] = hv;
      }
      __builtin_amdgcn_wave_barrier();
      {
        f32x4 h0 = *(const f32x4*)&T[n16 * 36 + q * 8];
        f32x4 h1 = *(const f32x4*)&T[n16 * 36 + q * 8 + 4];
        make_frags(h0, h1, b2h[nt], b2l[nt]);
      }
      __builtin_amdgcn_wave_barrier();
    }
    // ---- GEMM2: w2 frags from LDS, accumulate ----
    short8 a2h[8], a2l[8];
#pragma unroll
    for (int ms = 0; ms < 8; ++ms) {
      const int off = (ms * 4 + ko) * 512 + lane16;
      a2h[ms] = *(const short8*)(w2h_l + off);
      a2l[ms] = *(const short8*)(w2l_l + off);
    }
#pragma unroll
    for (int ms = 0; ms < 8; ++ms)
#pragma unroll
      for (int nt = 0; nt < 4; ++nt) {
        acc2[nt][ms] = mfma16(a2h[ms], b2h[nt], acc2[nt][ms]);
        acc2[nt][ms] = mfma16(a2l[ms], b2h[nt], acc2[nt][ms]);
        acc2[nt][ms] = mfma16(a2h[ms], b2l[nt], acc2[nt][ms]);
      }
  }

  // ---- epilogue: residual + lrelu + mask ----
  float mk[4];
#pragma unroll
  for (int nt = 0; nt < 4; ++nt) mk[nt] = maskp[(g0i + nt) * 16 + n16];
  f32x4 vsum[8];
  float po[4][3];
  if (!LAST) {
#pragma unroll
    for (int ms = 0; ms < 8; ++ms) vsum[ms] = (f32x4){0.f, 0.f, 0.f, 0.f};
  } else {
#pragma unroll
    for (int nt = 0; nt < 4; ++nt) po[nt][0] = po[nt][1] = po[nt][2] = 0.f;
  }
#pragma unroll
  for (int nt = 0; nt < 4; ++nt) {
    float* base_nt = xlf + (size_t)(g0i + nt) * 2048;
#pragma unroll
    for (int ms = 0; ms < 8; ++ms) {
      f32x4 lb4 = *(const f32x4*)&l2b_s[ms * 16 + q * 4];
      float* xo = base_nt + ms * 256 + (q * 16 + n16) * 4;
      f32x4 old = *(const f32x4*)xo;
      f32x4 v;
#pragma unroll
      for (int r = 0; r < 4; ++r) v[r] = lrelu(acc2[nt][ms][r] + lb4[r] + old[r]) * mk[nt];
      if (!LAST) {
        *(f32x4*)xo = v;
        vsum[ms] += v;
      } else {
        f32x4 w0 = *(const f32x4*)&outw_s[0 * 128 + ms * 16 + q * 4];
        f32x4 w1 = *(const f32x4*)&outw_s[1 * 128 + ms * 16 + q * 4];
        f32x4 w2 = *(const f32x4*)&outw_s[2 * 128 + ms * 16 + q * 4];
#pragma unroll
        for (int r = 0; r < 4; ++r) {
          po[nt][0] += v[r] * w0[r];
          po[nt][1] += v[r] * w1[r];
          po[nt][2] += v[r] * w2[r];
        }
      }
    }
  }
  if (LAST) {
#pragma unroll
    for (int nt = 0; nt < 4; ++nt)
#pragma unroll
      for (int o = 0; o < 3; ++o) {
        float s = po[nt][o];
        s += __shfl_xor(s, 16, 64);
        s += __shfl_xor(s, 32, 64);
        po[nt][o] = s;
      }
    if (q == 0) {
#pragma unroll
      for (int nt = 0; nt < 4; ++nt) {
        const int p = (g0i + nt) * 16 + n16;
#pragma unroll
        for (int o = 0; o < 3; ++o)
          outp[(size_t)p * 3 + o] = (po[nt][o] + outw_s[384 + o]) * mk[nt];
      }
    }
    return;
  }
  // partial sums: reduce over point lanes
#pragma unroll
  for (int ms = 0; ms < 8; ++ms) {
    f32x4 sr;
#pragma unroll
    for (int r = 0; r < 4; ++r) {
      float s = vsum[ms][r];
      s += __shfl_xor(s, 1, 64);
      s += __shfl_xor(s, 2, 64);
      s += __shfl_xor(s, 4, 64);
      s += __shfl_xor(s, 8, 64);
      sr[r] = s;
    }
    if (n16 == 0) *(f32x4*)&wsum[wv * 128 + ms * 16 + q * 4] = sr;
  }
  __syncthreads();
  if (tid < 128) {
    float s = 0.f;
#pragma unroll
    for (int w = 0; w < 8; ++w) s += wsum[w * 128 + tid];
    agent_store(&pP[(size_t)bid * 128 + tid], s);
  }

  // ---- winner tail: next block's global path ----
  __syncthreads();
  if (tid == 0) winflag = (atomicAdd(&counters_blk[b], 1u) == 15u) ? 1 : 0;
  __syncthreads();
  if (!winflag) return;
  epic_global_tail<16>(b, tid, pP, cnt_g[b], xg_tail_cur + b * 16, xg_tail_next + b * 16,
                       context, g1w_n, g1b_n, g2w_n, g2b_n, l1w_n, l1b_n,
                       gbias_tail_out + (size_t)b * 128, shx);
}

extern "C" void kernel_launch(void* const* d_in, const int* in_sizes, int n_in,
                              void* d_out, int out_size, void* d_ws, size_t ws_size,
                              hipStream_t stream) {
  const float* x_local = (const float*)d_in[0];
  const float* context = (const float*)d_in[1];
  const float* mask = (const float*)d_in[2];
  const float* proj_lw = (const float*)d_in[3];
  const float* proj_lb = (const float*)d_in[4];
  const float* proj_g0w = (const float*)d_in[5];
  const float* proj_g0b = (const float*)d_in[6];
  const float* proj_g1w = (const float*)d_in[7];
  const float* proj_g1b = (const float*)d_in[8];
  const float* proj_g2w = (const float*)d_in[9];
  const float* proj_g2b = (const float*)d_in[10];
  const float* g1w = (const float*)d_in[11];
  const float* g1b = (const float*)d_in[12];
  const float* g2w = (const float*)d_in[13];
  const float* g2b = (const float*)d_in[14];
  const float* l1w = (const float*)d_in[15];
  const float* l1b = (const float*)d_in[16];
  const float* l2w = (const float*)d_in[17];
  const float* l2b = (const float*)d_in[18];
  const float* outw = (const float*)d_in[19];
  const float* outb = (const float*)d_in[20];
  float* out = (float*)d_out;

  char* ws = (char*)d_ws;
  float* xlf = (float*)ws;                                  // 67,108,864
  float* pP = (float*)(ws + 67108864);                      //  1,048,576
  float* cntp = (float*)(ws + 68157440);                    //      4,096
  float* cnt_g = (float*)(ws + 68161536);                   //         64
  float* xg_g = (float*)(ws + 68161600);                    //      7,168
  float* gbias_g = (float*)(ws + 68168768);                 //     49,152
  unsigned int* counters = (unsigned int*)(ws + 68217920);  //        448
  unsigned short* w1h = (unsigned short*)(ws + 68218368);   //    196,608
  unsigned short* w1l = (unsigned short*)(ws + 68414976);   //    196,608
  unsigned short* w2h = (unsigned short*)(ws + 68611584);   //    196,608
  unsigned short* w2l = (unsigned short*)(ws + 68808192);   //    196,608
  // end: 69,004,800 (< proven 70,018,304)

  prep_weights<<<384, 256, 0, stream>>>(l1w, l2w, w1h, w1l, w2h, w2l, counters);
  proj_local_kernel<<<1024, 256, 0, stream>>>(
      x_local, mask, proj_lw, proj_lb, xlf, pP, cntp, cnt_g, counters, context,
      proj_g0w, proj_g0b, proj_g1w, proj_g1b, proj_g2w, proj_g2b, xg_g,
      g1w, g1b, g2w, g2b, l1w, l1b, gbias_g);
  for (int i = 0; i < NB_; ++i) {
    const int j = i + 1;  // next block (tail target)
    const float* g1w_n = g1w + (size_t)j * 128 * 282;
    const float* g1b_n = g1b + j * 128;
    const float* g2w_n = g2w + j * 10 * 128;
    const float* g2b_n = g2b + j * 10;
    const float* l1w_n = l1w + (size_t)j * 128 * 154;
    const float* l1b_n = l1b + j * 128;
    const unsigned short* w1h_i = w1h + i * 16384;
    const unsigned short* w1l_i = w1l + i * 16384;
    const unsigned short* w2h_i = w2h + i * 16384;
    const unsigned short* w2l_i = w2l + i * 16384;
    if (i == NB_ - 1) {
      epic_local_kernel<true><<<256, 512, 0, stream>>>(
          xlf, pP, cnt_g, counters + (i + 1) * 16, gbias_g + (size_t)(i * 16) * 128,
          nullptr, nullptr, nullptr, context,
          nullptr, nullptr, nullptr, nullptr, nullptr, nullptr,
          l2b + i * 128, w1h_i, w1l_i, w2h_i, w2l_i, mask, outw, outb, out);
    } else {
      epic_local_kernel<false><<<256, 512, 0, stream>>>(
          xlf, pP, cnt_g, counters + (i + 1) * 16, gbias_g + (size_t)(i * 16) * 128,
          xg_g + (i + 1) * 16 * 16, xg_g + (i + 2) * 16 * 16,
          gbias_g + (size_t)((i + 1) * 16) * 128, context,
          g1w_n, g1b_n, g2w_n, g2b_n, l1w_n, l1b_n,
          l2b + i * 128, w1h_i, w1l_i, w2h_i, w2l_i, mask, outw, outb, out);
    }
  }
}

// Round 11
// 477.069 us; speedup vs baseline: 1.4730x; 1.4730x over previous
//
#include <hip/hip_runtime.h>
#include <hip/hip_bf16.h>

// EPiC network, round 11: LDS-resident weights, 512-thr WGs, 32 pts/wave.
// r10 spilled (64 pts/wave needs ~330 regs > 256 budget at 2 waves/SIMD ->
// 290 MB scratch traffic). r11: nt=2 (32 pts/wave) + chunked frag loads
// -> ~210 unified regs, no spills, keeps 2 waves/SIMD for latency overlap.
// - Weights pre-split (hi/lo bf16) + frag-order swizzle (r9): fragment read =
//   ds_read_b128 at blockbase + lane*16 (conflict-free, global_load_lds-compatible).
// - epic WG: 512 thr / 8 waves x 32 pts = 256 pts, 512 WGs, 1 WG/CU (LDS ~154 KB).
// - Truncating hi-split: hi = x & 0xffff0000, lo = RNE(x - hi).
// - xl state: fp32 16-pt-group frag layout (r8).
// - Winner-tail global path + agent-scope write-through publication (r7).
// - Split-bf16 3-term emulation: A*B ~= Ah*Bh + Al*Bh + Ah*Bl.

typedef __attribute__((ext_vector_type(8))) short short8;
typedef __attribute__((ext_vector_type(4))) float f32x4;

#define B_ 16
#define N_ 8192
#define DC_ 16
#define H_ 128
#define G_ 10
#define NB_ 6
#define NEG_ 0.01f

__device__ __forceinline__ float lrelu(float x) { return x > 0.f ? x : NEG_ * x; }

__device__ __forceinline__ unsigned short f2bf(float x) {
  union { float f; unsigned u; } v; v.f = x;
  return (unsigned short)((v.u + 0x7fffu + ((v.u >> 16) & 1u)) >> 16);  // RNE
}
__device__ __forceinline__ float bf2f(unsigned short u) {
  union { unsigned u; float f; } v; v.u = ((unsigned)u) << 16; return v.f;
}
// truncating hi (1 op) + RNE lo of residual; pair represents x to ~2^-17
__device__ __forceinline__ void split_bf(float x, unsigned short& h, unsigned short& l) {
  union { float f; unsigned u; } v; v.f = x;
  unsigned hu = v.u & 0xffff0000u;
  h = (unsigned short)(hu >> 16);
  union { unsigned u; float f; } hv; hv.u = hu;
  l = f2bf(x - hv.f);
}

__device__ __forceinline__ f32x4 mfma16(short8 a, short8 b, f32x4 c) {
  return __builtin_amdgcn_mfma_f32_16x16x32_bf16(a, b, c, 0, 0, 0);
}

__device__ __forceinline__ void make_frags(f32x4 v0, f32x4 v1, short8& bh, short8& bl) {
  unsigned short h, l;
#pragma unroll
  for (int j = 0; j < 4; ++j) {
    split_bf(v0[j], h, l);
    bh[j] = (short)h; bl[j] = (short)l;
  }
#pragma unroll
  for (int j = 0; j < 4; ++j) {
    split_bf(v1[j], h, l);
    bh[4 + j] = (short)h; bl[4 + j] = (short)l;
  }
}

// async 16B-per-lane global -> LDS copy (lane-contiguous DMA)
__device__ __forceinline__ void async_cp16(const void* g, void* l) {
  __builtin_amdgcn_global_load_lds(
      (const __attribute__((address_space(1))) void*)g,
      (__attribute__((address_space(3))) void*)l, 16, 0, 0);
}

// agent-scope write-through publication (no L2 flush)
__device__ __forceinline__ void agent_store(float* p, float v) {
  __hip_atomic_store(p, v, __ATOMIC_RELAXED, __HIP_MEMORY_SCOPE_AGENT);
}
__device__ __forceinline__ float agent_load(const float* p) {
  return __hip_atomic_load(p, __ATOMIC_RELAXED, __HIP_MEMORY_SCOPE_AGENT);
}

// ---- common tail: pool(NS slots) -> h_g -> xg residual -> folded gbias ----
// Works for blockDim 256 or 512: compute guarded, barriers unconditional.
template <int NS>
__device__ void epic_global_tail(
    int b, int tid, const float* __restrict__ pP, float cnt,
    const float* __restrict__ xg_cur, float* __restrict__ xg_next,
    const float* __restrict__ context,
    const float* __restrict__ g1w_n, const float* __restrict__ g1b_n,
    const float* __restrict__ g2w_n, const float* __restrict__ g2b_n,
    const float* __restrict__ l1w_n, const float* __restrict__ l1b_n,
    float* __restrict__ gbias_out, float* shx) {
  if (tid < 256) {
    const int f = tid & 127, kh = tid >> 7;
    const float* pr = pP + ((size_t)b * NS + kh * (NS / 2)) * 128 + f;
    float s = 0.f;
#pragma unroll 8
    for (int w = 0; w < NS / 2; ++w) s += agent_load(pr + w * 128);
    shx[tid] = s;
  }
  __syncthreads();
  if (tid < 128) {
    float s = shx[tid] + shx[tid + 128];
    shx[384 + tid] = s;
    shx[256 + tid] = s / cnt;
  }
  if (tid < G_) shx[512 + tid] = xg_cur[tid];
  if (tid >= 32 && tid < 32 + DC_) shx[522 + tid - 32] = context[b * DC_ + tid - 32];
  __syncthreads();
  if (tid < 256) {
    const int f = tid & 127, kh = tid >> 7;
    const float* wr = g1w_n + (size_t)f * 282 + kh * 142;
    const float* vp = shx + 256 + kh * 142;
    const int n2 = kh ? 70 : 71;
    float a = 0.f;
#pragma unroll 8
    for (int j = 0; j < n2; ++j) {
      float2 w2 = *(const float2*)(wr + 2 * j);
      a += w2.x * vp[2 * j] + w2.y * vp[2 * j + 1];
    }
    shx[tid] = a;  // writes 0..255; reads were 256..539 (disjoint)
  }
  __syncthreads();
  if (tid < 128) shx[544 + tid] = lrelu(shx[tid] + shx[tid + 128] + g1b_n[tid]);
  __syncthreads();
  if (tid < G_) {
    const float* wr = g2w_n + tid * 128;
    float a = g2b_n[tid] + shx[512 + tid];
#pragma unroll 8
    for (int j = 0; j < 32; ++j) {
      float4 w4 = *(const float4*)(wr + 4 * j);
      a += w4.x * shx[544 + 4 * j] + w4.y * shx[544 + 4 * j + 1] +
           w4.z * shx[544 + 4 * j + 2] + w4.w * shx[544 + 4 * j + 3];
    }
    float v = lrelu(a);
    shx[672 + tid] = v;
    xg_next[tid] = v;
  }
  __syncthreads();
  if (tid < 128) {
    const float* wr = l1w_n + tid * 154;
    float a = l1b_n[tid];
#pragma unroll
    for (int j = 0; j < G_; ++j) a += wr[128 + j] * shx[672 + j];
#pragma unroll
    for (int j = 0; j < DC_; ++j) a += wr[138 + j] * shx[522 + j];
    gbias_out[tid] = a;
  }
}

// ---------------- weight prep: split + frag-order swizzle ----------------
// dest off for (F,k): mt=F>>4, r=F&15, ks=k>>5, c=k&31:
//   (mt*4+ks)*512 + ((c>>3)*16 + r)*8 + (c&7)
__global__ __launch_bounds__(256) void prep_weights(
    const float* __restrict__ l1w, const float* __restrict__ l2w,
    unsigned short* __restrict__ w1h, unsigned short* __restrict__ w1l,
    unsigned short* __restrict__ w2h, unsigned short* __restrict__ w2l,
    unsigned int* __restrict__ counters) {
  int idx = blockIdx.x * 256 + threadIdx.x;
  const int total = NB_ * H_ * H_;
  if (idx < 112) counters[idx] = 0u;
  if (idx < total) {
    int i = idx / (H_ * H_), rem = idx % (H_ * H_);
    int F = rem / H_, k = rem % H_;
    int mt = F >> 4, r = F & 15, ks = k >> 5, c = k & 31;
    int off = i * 16384 + (mt * 4 + ks) * 512 + ((c >> 3) * 16 + r) * 8 + (c & 7);
    unsigned short h, l;
    split_bf(l1w[(i * H_ + F) * 154 + k], h, l);
    w1h[off] = h; w1l[off] = l;
    split_bf(l2w[(i * H_ + F) * H_ + k], h, l);
    w2h[off] = h; w2l[off] = l;
  }
}

// ---------------- projection local (writes 16-pt-group xl) + proj/blk0 tail ----
__global__ __launch_bounds__(256, 2) void proj_local_kernel(
    const float* __restrict__ xloc, const float* __restrict__ maskp,
    const float* __restrict__ plw, const float* __restrict__ plb,
    float* __restrict__ xlf, float* __restrict__ pP,
    float* __restrict__ cntp, float* __restrict__ cnt_g,
    unsigned int* __restrict__ counters,
    const float* __restrict__ context,
    const float* __restrict__ g0w, const float* __restrict__ g0b,
    const float* __restrict__ g1pw, const float* __restrict__ g1pb,
    const float* __restrict__ g2pw, const float* __restrict__ g2pb,
    float* __restrict__ xg_g,
    const float* __restrict__ g1w0, const float* __restrict__ g1b0,
    const float* __restrict__ g2w0, const float* __restrict__ g2b0,
    const float* __restrict__ l1w0, const float* __restrict__ l1b0,
    float* __restrict__ gbias_g) {
  __shared__ float wq[H_][4];
  __shared__ float wsum[512];
  __shared__ float cw[4];
  __shared__ float shx[768];
  __shared__ int winflag;
  const int tid = threadIdx.x, bid = blockIdx.x;
  const int wv = tid >> 6, lane = tid & 63;
  const int q = lane >> 4, n16 = lane & 15;
  const int b = bid >> 6;
  if (tid < H_) {
    wq[tid][0] = plw[tid * 3 + 0];
    wq[tid][1] = plw[tid * 3 + 1];
    wq[tid][2] = plw[tid * 3 + 2];
    wq[tid][3] = plb[tid];
  }
  __syncthreads();
  const int t = bid * 4 + wv;            // 32-pt tile index
  const int p0 = t * 32;
  const int pa = p0 + n16, pb = p0 + 16 + n16;
  const float xa0 = xloc[pa * 3], xa1 = xloc[pa * 3 + 1], xa2 = xloc[pa * 3 + 2];
  const float xb0 = xloc[pb * 3], xb1 = xloc[pb * 3 + 1], xb2 = xloc[pb * 3 + 2];
  const float m0 = maskp[pa], m1 = maskp[pb];
  float* ga = xlf + (size_t)(2 * t) * 2048;
  float* gb = ga + 2048;
#pragma unroll
  for (int ms = 0; ms < 8; ++ms) {
    f32x4 v0, v1;
#pragma unroll
    for (int r = 0; r < 4; ++r) {
      const int F = ms * 16 + q * 4 + r;
      float4 w4 = *(const float4*)wq[F];
      v0[r] = lrelu(w4.x * xa0 + w4.y * xa1 + w4.z * xa2 + w4.w) * m0;
      v1[r] = lrelu(w4.x * xb0 + w4.y * xb1 + w4.z * xb2 + w4.w) * m1;
    }
    *(f32x4*)(ga + ms * 256 + (q * 16 + n16) * 4) = v0;
    *(f32x4*)(gb + ms * 256 + (q * 16 + n16) * 4) = v1;
    f32x4 s = v0 + v1;
#pragma unroll
    for (int r = 0; r < 4; ++r) {
      float sv = s[r];
      sv += __shfl_xor(sv, 1, 64);
      sv += __shfl_xor(sv, 2, 64);
      sv += __shfl_xor(sv, 4, 64);
      sv += __shfl_xor(sv, 8, 64);
      s[r] = sv;
    }
    if (n16 == 0) *(f32x4*)&wsum[wv * 128 + ms * 16 + q * 4] = s;
  }
  {
    float c = (q == 0) ? (m0 + m1) : 0.f;
    c += __shfl_xor(c, 1, 64);
    c += __shfl_xor(c, 2, 64);
    c += __shfl_xor(c, 4, 64);
    c += __shfl_xor(c, 8, 64);
    if (lane == 0) cw[wv] = c;
  }
  __syncthreads();
  // two 64-pt slots per WG -> 128 slots per batch
  if (tid < 128) {
    agent_store(&pP[(size_t)(2 * bid) * 128 + tid], wsum[tid] + wsum[128 + tid]);
    agent_store(&pP[(size_t)(2 * bid + 1) * 128 + tid], wsum[256 + tid] + wsum[384 + tid]);
  }
  if (tid == 0) agent_store(&cntp[bid], cw[0] + cw[1] + cw[2] + cw[3]);

  // ---- winner tail: proj global path + block-0 global path ----
  __syncthreads();
  if (tid == 0) winflag = (atomicAdd(&counters[b], 1u) == 63u) ? 1 : 0;
  __syncthreads();
  if (!winflag) return;
  if (tid < 64) shx[688 + tid] = agent_load(&cntp[b * 64 + tid]);
  __syncthreads();
  if (tid == 0) {
    float c = 0.f;
#pragma unroll
    for (int w = 0; w < 64; ++w) c += shx[688 + w];
    shx[752] = c;
    cnt_g[b] = c;
  }
  __syncthreads();
  const float cnt = shx[752];
  {
    const int f = tid & 127, kh = tid >> 7;
    const float* pr = pP + ((size_t)b * 128 + kh * 64) * 128 + f;
    float s = 0.f;
#pragma unroll 8
    for (int w = 0; w < 64; ++w) s += agent_load(pr + w * 128);
    shx[tid] = s;
  }
  __syncthreads();
  if (tid < 128) {
    float s = shx[tid] + shx[tid + 128];
    shx[384 + tid] = s;
    shx[256 + tid] = s / cnt;
  }
  if (tid < DC_) shx[512 + tid] = context[b * DC_ + tid];
  __syncthreads();
  {
    const int f = tid & 127, kh = tid >> 7;
    const float* wr = g0w + (size_t)f * 272 + kh * 136;
    const float* vp = shx + 256 + kh * 136;
    float a = 0.f;
#pragma unroll 8
    for (int j = 0; j < 34; ++j) {
      float4 w4 = *(const float4*)(wr + 4 * j);
      a += w4.x * vp[4 * j] + w4.y * vp[4 * j + 1] + w4.z * vp[4 * j + 2] + w4.w * vp[4 * j + 3];
    }
    __syncthreads();
    shx[tid] = a;
  }
  __syncthreads();
  if (tid < 128) shx[544 + tid] = lrelu(shx[tid] + shx[tid + 128] + g0b[tid]);
  __syncthreads();
  {
    const int f = tid & 127, kh = tid >> 7;
    const float* wr = g1pw + (size_t)f * 128 + kh * 64;
    const float* vp = shx + 544 + kh * 64;
    float a = 0.f;
#pragma unroll 8
    for (int j = 0; j < 16; ++j) {
      float4 w4 = *(const float4*)(wr + 4 * j);
      a += w4.x * vp[4 * j] + w4.y * vp[4 * j + 1] + w4.z * vp[4 * j + 2] + w4.w * vp[4 * j + 3];
    }
    __syncthreads();
    shx[tid] = a;
  }
  __syncthreads();
  if (tid < 128) shx[544 + tid] = lrelu(shx[tid] + shx[tid + 128] + g1pb[tid]);
  __syncthreads();
  if (tid < G_) {
    const float* wr = g2pw + tid * 128;
    float a = g2pb[tid];
#pragma unroll 8
    for (int j = 0; j < 32; ++j) {
      float4 w4 = *(const float4*)(wr + 4 * j);
      a += w4.x * shx[544 + 4 * j] + w4.y * shx[544 + 4 * j + 1] +
           w4.z * shx[544 + 4 * j + 2] + w4.w * shx[544 + 4 * j + 3];
    }
    xg_g[(0 * 16 + b) * 16 + tid] = lrelu(a);
  }
  __syncthreads();
  epic_global_tail<128>(b, tid, pP, cnt,
                        xg_g + (0 * 16 + b) * 16, xg_g + (1 * 16 + b) * 16, context,
                        g1w0, g1b0, g2w0, g2b0, l1w0, l1b0,
                        gbias_g + (size_t)(0 * 16 + b) * 128, shx);
}

// ---------------- epic local: LDS-weight GEMMs, 8 waves x 32 pts ----------------
template <bool LAST>
__global__ __launch_bounds__(512, 2) void epic_local_kernel(
    float* __restrict__ xlf, float* __restrict__ pP,
    const float* __restrict__ cnt_g, unsigned int* __restrict__ counters_blk,
    const float* __restrict__ gbias_in,
    const float* __restrict__ xg_tail_cur, float* __restrict__ xg_tail_next,
    float* __restrict__ gbias_tail_out,
    const float* __restrict__ context,
    const float* __restrict__ g1w_n, const float* __restrict__ g1b_n,
    const float* __restrict__ g2w_n, const float* __restrict__ g2b_n,
    const float* __restrict__ l1w_n, const float* __restrict__ l1b_n,
    const float* __restrict__ l2b,
    const unsigned short* __restrict__ w1h, const unsigned short* __restrict__ w1l,
    const unsigned short* __restrict__ w2h, const unsigned short* __restrict__ w2l,
    const float* __restrict__ maskp,
    const float* __restrict__ outw, const float* __restrict__ outb,
    float* __restrict__ outp) {
  __shared__ unsigned short wbuf[65536];  // 128 KB: w1h|w1l|w2h|w2l, 16384 shorts each
  __shared__ float tiles[8][576];
  __shared__ float shx[768];
  __shared__ float gbias_s[128];
  __shared__ float l2b_s[128];
  __shared__ float wsum[1024];
  __shared__ float outw_s[392];
  __shared__ int winflag;
  const int tid = threadIdx.x, bid = blockIdx.x;
  const int b = bid >> 5;  // 32 WGs per batch
  const int wv = tid >> 6, lane = tid & 63;
  const int q = lane >> 4, n16 = lane & 15;

  // ---- stage weights: wave wv stages 16 KB (16 x 1KB async) ----
  {
    const unsigned short* src =
        (wv < 2) ? w1h : (wv < 4) ? w1l : (wv < 6) ? w2h : w2l;
    const char* s8 = (const char*)(src + (wv & 1) * 8192) + lane * 16;
    char* d8 = (char*)wbuf + wv * 16384;
#pragma unroll
    for (int j = 0; j < 16; ++j) async_cp16(s8 + j * 1024, d8 + j * 1024);
  }
  if (tid < 128) {
    gbias_s[tid] = gbias_in[b * 128 + tid];
    l2b_s[tid] = l2b[tid];
  }
  if (LAST) {
    if (tid < 384) outw_s[tid] = outw[tid];
    if (tid >= 384 && tid < 387) outw_s[tid] = outb[tid - 384];
  }

  // ---- x B-frags for 2 groups (32 points): 64 VGPR persistent ----
  const int g0i = bid * 16 + wv * 2;  // first 16-pt group of this wave
  short8 xbh[2][4], xbl[2][4];
#pragma unroll
  for (int nt = 0; nt < 2; ++nt) {
    const float* base_nt = xlf + (size_t)(g0i + nt) * 2048;
#pragma unroll
    for (int ks = 0; ks < 4; ++ks) {
      const float* pb = base_nt + (2 * ks + (q >> 1)) * 256 + ((q & 1) * 32 + n16) * 4;
      f32x4 v0 = *(const f32x4*)pb;
      f32x4 v1 = *(const f32x4*)(pb + 64);
      make_frags(v0, v1, xbh[nt][ks], xbl[nt][ks]);
    }
  }
  __syncthreads();  // staging drained (vmcnt 0) + all waves ready

  const unsigned short* w1h_l = wbuf;
  const unsigned short* w1l_l = wbuf + 16384;
  const unsigned short* w2h_l = wbuf + 32768;
  const unsigned short* w2l_l = wbuf + 49152;
  float* T = tiles[wv];
  const int lane16 = lane * 8;  // shorts

  f32x4 acc2[2][8];
#pragma unroll
  for (int nt = 0; nt < 2; ++nt)
#pragma unroll
    for (int ms = 0; ms < 8; ++ms) acc2[nt][ms] = (f32x4){0.f, 0.f, 0.f, 0.f};

#pragma unroll
  for (int ko = 0; ko < 4; ++ko) {
    // ---- GEMM1: w1 frags from LDS, chunked per msl (32 transient regs) ----
    f32x4 acc[2][2];
#pragma unroll
    for (int nt = 0; nt < 2; ++nt)
#pragma unroll
      for (int msl = 0; msl < 2; ++msl) acc[nt][msl] = (f32x4){0.f, 0.f, 0.f, 0.f};
#pragma unroll
    for (int msl = 0; msl < 2; ++msl) {
      short8 a1h[4], a1l[4];
#pragma unroll
      for (int ks = 0; ks < 4; ++ks) {
        const int off = ((ko * 2 + msl) * 4 + ks) * 512 + lane16;
        a1h[ks] = *(const short8*)(w1h_l + off);
        a1l[ks] = *(const short8*)(w1l_l + off);
      }
#pragma unroll
      for (int ks = 0; ks < 4; ++ks)
#pragma unroll
        for (int nt = 0; nt < 2; ++nt) {
          acc[nt][msl] = mfma16(a1h[ks], xbh[nt][ks], acc[nt][msl]);
          acc[nt][msl] = mfma16(a1l[ks], xbh[nt][ks], acc[nt][msl]);
          acc[nt][msl] = mfma16(a1h[ks], xbl[nt][ks], acc[nt][msl]);
        }
    }
    // ---- per nt: lrelu+gbias, tile round-trip -> b2 frags ----
    short8 b2h[2], b2l[2];
#pragma unroll
    for (int nt = 0; nt < 2; ++nt) {
#pragma unroll
      for (int msl = 0; msl < 2; ++msl) {
        f32x4 gb4 = *(const f32x4*)&gbias_s[(ko * 2 + msl) * 16 + q * 4];
        f32x4 hv;
#pragma unroll
        for (int r = 0; r < 4; ++r) hv[r] = lrelu(acc[nt][msl][r] + gb4[r]);
        *(f32x4*)&T[n16 * 36 + msl * 16 + q * 4] = hv;
      }
      __builtin_amdgcn_wave_barrier();
      {
        f32x4 h0 = *(const f32x4*)&T[n16 * 36 + q * 8];
        f32x4 h1 = *(const f32x4*)&T[n16 * 36 + q * 8 + 4];
        make_frags(h0, h1, b2h[nt], b2l[nt]);
      }
      __builtin_amdgcn_wave_barrier();
    }
    // ---- GEMM2: w2 frags from LDS, chunked per 4 ms (32 transient regs) ----
#pragma unroll
    for (int half = 0; half < 2; ++half) {
      short8 a2h[4], a2l[4];
#pragma unroll
      for (int mi = 0; mi < 4; ++mi) {
        const int off = ((half * 4 + mi) * 4 + ko) * 512 + lane16;
        a2h[mi] = *(const short8*)(w2h_l + off);
        a2l[mi] = *(const short8*)(w2l_l + off);
      }
#pragma unroll
      for (int mi = 0; mi < 4; ++mi)
#pragma unroll
        for (int nt = 0; nt < 2; ++nt) {
          acc2[nt][half * 4 + mi] = mfma16(a2h[mi], b2h[nt], acc2[nt][half * 4 + mi]);
          acc2[nt][half * 4 + mi] = mfma16(a2l[mi], b2h[nt], acc2[nt][half * 4 + mi]);
          acc2[nt][half * 4 + mi] = mfma16(a2h[mi], b2l[nt], acc2[nt][half * 4 + mi]);
        }
    }
  }

  // ---- epilogue: residual + lrelu + mask ----
  float mk[2];
#pragma unroll
  for (int nt = 0; nt < 2; ++nt) mk[nt] = maskp[(g0i + nt) * 16 + n16];
  f32x4 vsum[8];
  float po[2][3];
  if (!LAST) {
#pragma unroll
    for (int ms = 0; ms < 8; ++ms) vsum[ms] = (f32x4){0.f, 0.f, 0.f, 0.f};
  } else {
#pragma unroll
    for (int nt = 0; nt < 2; ++nt) po[nt][0] = po[nt][1] = po[nt][2] = 0.f;
  }
#pragma unroll
  for (int nt = 0; nt < 2; ++nt) {
    float* base_nt = xlf + (size_t)(g0i + nt) * 2048;
#pragma unroll
    for (int ms = 0; ms < 8; ++ms) {
      f32x4 lb4 = *(const f32x4*)&l2b_s[ms * 16 + q * 4];
      float* xo = base_nt + ms * 256 + (q * 16 + n16) * 4;
      f32x4 old = *(const f32x4*)xo;
      f32x4 v;
#pragma unroll
      for (int r = 0; r < 4; ++r) v[r] = lrelu(acc2[nt][ms][r] + lb4[r] + old[r]) * mk[nt];
      if (!LAST) {
        *(f32x4*)xo = v;
        vsum[ms] += v;
      } else {
        f32x4 w0 = *(const f32x4*)&outw_s[0 * 128 + ms * 16 + q * 4];
        f32x4 w1 = *(const f32x4*)&outw_s[1 * 128 + ms * 16 + q * 4];
        f32x4 w2 = *(const f32x4*)&outw_s[2 * 128 + ms * 16 + q * 4];
#pragma unroll
        for (int r = 0; r < 4; ++r) {
          po[nt][0] += v[r] * w0[r];
          po[nt][1] += v[r] * w1[r];
          po[nt][2] += v[r] * w2[r];
        }
      }
    }
  }
  if (LAST) {
#pragma unroll
    for (int nt = 0; nt < 2; ++nt)
#pragma unroll
      for (int o = 0; o < 3; ++o) {
        float s = po[nt][o];
        s += __shfl_xor(s, 16, 64);
        s += __shfl_xor(s, 32, 64);
        po[nt][o] = s;
      }
    if (q == 0) {
#pragma unroll
      for (int nt = 0; nt < 2; ++nt) {
        const int p = (g0i + nt) * 16 + n16;
#pragma unroll
        for (int o = 0; o < 3; ++o)
          outp[(size_t)p * 3 + o] = (po[nt][o] + outw_s[384 + o]) * mk[nt];
      }
    }
    return;
  }
  // partial sums: reduce over point lanes
#pragma unroll
  for (int ms = 0; ms < 8; ++ms) {
    f32x4 sr;
#pragma unroll
    for (int r = 0; r < 4; ++r) {
      float s = vsum[ms][r];
      s += __shfl_xor(s, 1, 64);
      s += __shfl_xor(s, 2, 64);
      s += __shfl_xor(s, 4, 64);
      s += __shfl_xor(s, 8, 64);
      sr[r] = s;
    }
    if (n16 == 0) *(f32x4*)&wsum[wv * 128 + ms * 16 + q * 4] = sr;
  }
  __syncthreads();
  if (tid < 128) {
    float s = 0.f;
#pragma unroll
    for (int w = 0; w < 8; ++w) s += wsum[w * 128 + tid];
    agent_store(&pP[(size_t)bid * 128 + tid], s);
  }

  // ---- winner tail: next block's global path ----
  __syncthreads();
  if (tid == 0) winflag = (atomicAdd(&counters_blk[b], 1u) == 31u) ? 1 : 0;
  __syncthreads();
  if (!winflag) return;
  epic_global_tail<32>(b, tid, pP, cnt_g[b], xg_tail_cur + b * 16, xg_tail_next + b * 16,
                       context, g1w_n, g1b_n, g2w_n, g2b_n, l1w_n, l1b_n,
                       gbias_tail_out + (size_t)b * 128, shx);
}

extern "C" void kernel_launch(void* const* d_in, const int* in_sizes, int n_in,
                              void* d_out, int out_size, void* d_ws, size_t ws_size,
                              hipStream_t stream) {
  const float* x_local = (const float*)d_in[0];
  const float* context = (const float*)d_in[1];
  const float* mask = (const float*)d_in[2];
  const float* proj_lw = (const float*)d_in[3];
  const float* proj_lb = (const float*)d_in[4];
  const float* proj_g0w = (const float*)d_in[5];
  const float* proj_g0b = (const float*)d_in[6];
  const float* proj_g1w = (const float*)d_in[7];
  const float* proj_g1b = (const float*)d_in[8];
  const float* proj_g2w = (const float*)d_in[9];
  const float* proj_g2b = (const float*)d_in[10];
  const float* g1w = (const float*)d_in[11];
  const float* g1b = (const float*)d_in[12];
  const float* g2w = (const float*)d_in[13];
  const float* g2b = (const float*)d_in[14];
  const float* l1w = (const float*)d_in[15];
  const float* l1b = (const float*)d_in[16];
  const float* l2w = (const float*)d_in[17];
  const float* l2b = (const float*)d_in[18];
  const float* outw = (const float*)d_in[19];
  const float* outb = (const float*)d_in[20];
  float* out = (float*)d_out;

  char* ws = (char*)d_ws;
  float* xlf = (float*)ws;                                  // 67,108,864
  float* pP = (float*)(ws + 67108864);                      //  1,048,576
  float* cntp = (float*)(ws + 68157440);                    //      4,096
  float* cnt_g = (float*)(ws + 68161536);                   //         64
  float* xg_g = (float*)(ws + 68161600);                    //      7,168
  float* gbias_g = (float*)(ws + 68168768);                 //     49,152
  unsigned int* counters = (unsigned int*)(ws + 68217920);  //        448
  unsigned short* w1h = (unsigned short*)(ws + 68218368);   //    196,608
  unsigned short* w1l = (unsigned short*)(ws + 68414976);   //    196,608
  unsigned short* w2h = (unsigned short*)(ws + 68611584);   //    196,608
  unsigned short* w2l = (unsigned short*)(ws + 68808192);   //    196,608
  // end: 69,004,800 (< proven 70,018,304)

  prep_weights<<<384, 256, 0, stream>>>(l1w, l2w, w1h, w1l, w2h, w2l, counters);
  proj_local_kernel<<<1024, 256, 0, stream>>>(
      x_local, mask, proj_lw, proj_lb, xlf, pP, cntp, cnt_g, counters, context,
      proj_g0w, proj_g0b, proj_g1w, proj_g1b, proj_g2w, proj_g2b, xg_g,
      g1w, g1b, g2w, g2b, l1w, l1b, gbias_g);
  for (int i = 0; i < NB_; ++i) {
    const int j = i + 1;  // next block (tail target)
    const float* g1w_n = g1w + (size_t)j * 128 * 282;
    const float* g1b_n = g1b + j * 128;
    const float* g2w_n = g2w + j * 10 * 128;
    const float* g2b_n = g2b + j * 10;
    const float* l1w_n = l1w + (size_t)j * 128 * 154;
    const float* l1b_n = l1b + j * 128;
    const unsigned short* w1h_i = w1h + i * 16384;
    const unsigned short* w1l_i = w1l + i * 16384;
    const unsigned short* w2h_i = w2h + i * 16384;
    const unsigned short* w2l_i = w2l + i * 16384;
    if (i == NB_ - 1) {
      epic_local_kernel<true><<<512, 512, 0, stream>>>(
          xlf, pP, cnt_g, counters + (i + 1) * 16, gbias_g + (size_t)(i * 16) * 128,
          nullptr, nullptr, nullptr, context,
          nullptr, nullptr, nullptr, nullptr, nullptr, nullptr,
          l2b + i * 128, w1h_i, w1l_i, w2h_i, w2l_i, mask, outw, outb, out);
    } else {
      epic_local_kernel<false><<<512, 512, 0, stream>>>(
          xlf, pP, cnt_g, counters + (i + 1) * 16, gbias_g + (size_t)(i * 16) * 128,
          xg_g + (i + 1) * 16 * 16, xg_g + (i + 2) * 16 * 16,
          gbias_g + (size_t)((i + 1) * 16) * 128, context,
          g1w_n, g1b_n, g2w_n, g2b_n, l1w_n, l1b_n,
          l2b + i * 128, w1h_i, w1l_i, w2h_i, w2l_i, mask, outw, outb, out);
    }
  }
}